// Round 11
// baseline (5578.054 us; speedup 1.0000x reference)
//
#include <hip/hip_runtime.h>

// GRUNet: 2-layer GRU (B=128, T=512, I=64, H=256) + ReLU + FC(256->2).
// Round 11: r7 + PHASE-SPLIT round (l0 phase -> l1 phase) so every
// cross-WG h edge has compute between publish and poll.
//   A: l0-dot(s) (w0-3)          || sweep h1(s-2) (w4-7)
//   B: finish-l0, PUBLISH h0(s)  || stage x(s+1)  || l1-dot(s-1) (w4-7)
//   C: finish-l1, publish h1(s-1)|| sweep h0(s) (w0-3, AFTER publish,
//                                   with l1-dot as propagation window)
//   3 syncthreads/round (same as r7). Single-buffered LDS (phase order
//   makes every overwrite follow its readers). No WAR flags (r10-proven).
//   Mantissa-tag dataflow (2 LSBs, ring 3, tag cycle 4) r7 verbatim.
//   Register-resident weights, dot code, FC epilogue: r7 verbatim.

namespace {
constexpr int kB = 128, kT = 512, kI = 64, kH = 256, kBH = kB * kH;
constexpr int RPG = 16, NWG = 256, NT = 512;

// activation stage: [kseg 8][row 16][32], row stride 36, kseg stride 580
constexpr int SRS = 36;
constexpr int SKS = 16 * SRS + 4;          // 580
constexpr int O_S0 = 0;                    // h0(s-1) stage
constexpr int O_S1 = O_S0 + 8 * SKS;       // h1(s-2) stage
constexpr int O_X  = O_S1 + 8 * SKS;       // [16][68] x(s)
constexpr int O_PB = O_X + RPG * 68;       // partials [4][16][36]
constexpr int PBN  = 4 * 16 * 36;
constexpr int LDSF = O_PB + PBN;           // 12672 floats = 49.5 KB
}

using ull = unsigned long long;
using u32 = unsigned;

__device__ __forceinline__ float sigf(float v) { return 1.0f / (1.0f + expf(-v)); }
__device__ __forceinline__ float dot4(const float4 a, const float4 b) {
  return a.x * b.x + a.y * b.y + a.z * b.z + a.w * b.w;
}
__device__ __forceinline__ float red8(float v) {   // sum over kseg lanes (bits 3..5)
  v += __shfl_xor(v, 8);
  v += __shfl_xor(v, 16);
  v += __shfl_xor(v, 32);
  return v;
}
#define F4(p) (*(const float4*)(p))
#define AL(p)    __hip_atomic_load((p), __ATOMIC_RELAXED, __HIP_MEMORY_SCOPE_AGENT)
#define AS(p, v) __hip_atomic_store((p), (v), __ATOMIC_RELAXED, __HIP_MEMORY_SCOPE_AGENT)

__global__ __launch_bounds__(NT, 2) void gru_persistent(
    const float* __restrict__ x,
    const float* __restrict__ wih0, const float* __restrict__ whh0,
    const float* __restrict__ bih0, const float* __restrict__ bhh0,
    const float* __restrict__ wih1, const float* __restrict__ whh1,
    const float* __restrict__ bih1, const float* __restrict__ bhh1,
    const float* __restrict__ fcw, const float* __restrict__ fcb,
    u32* __restrict__ h0w,    // [3][B][H] tagged dwords
    u32* __restrict__ h1w,    // [3][B][H] tagged dwords
    float* __restrict__ out)
{
  __shared__ float lds[LDSF];

  const int bid = blockIdx.x;
  const int g   = bid >> 5;
  const int wg  = bid & 31;
  const int tid = threadIdx.x;
  const int r0  = g * RPG;
  const int j0  = wg * 8;

  const int wave = tid >> 6, lane = tid & 63;
  const int lay  = wave >> 2;          // waves 0-3: l0, 4-7: l1
  const int fam  = (wave >> 1) & 1;
  const int rh   = wave & 1;
  const int ju   = lane & 7;
  const int ks   = lane >> 3;
  const int jg   = j0 + ju;

  // zero partial buffer once (unwritten slots must stay 0 forever)
  for (int i = tid; i < PBN; i += NT) lds[O_PB + i] = 0.f;

  // ---- weight slices into registers (once) — r7 verbatim ----
  float4 wr0[8], wr1[8], wr2[8];
  if (lay == 0) {
    if (fam == 0) {
#define L0F0(wrg, gg) { \
      const float* wi = wih0 + (size_t)((gg) * kH + jg) * kI + ks * 8;   \
      const float* wh = whh0 + (size_t)((gg) * kH + jg) * kH + ks * 32;  \
      wrg[0] = F4(wi); wrg[1] = F4(wi + 4);                              \
      wrg[2] = F4(wh); wrg[3] = F4(wh + 4); wrg[4] = F4(wh + 8); }
      L0F0(wr0, 0) L0F0(wr1, 1) L0F0(wr2, 2)
    } else {
#define L0F1(wrg, gg) { \
      const float* wh = whh0 + (size_t)((gg) * kH + jg) * kH + ks * 32 + 12; \
      wrg[0] = F4(wh); wrg[1] = F4(wh + 4); wrg[2] = F4(wh + 8);             \
      wrg[3] = F4(wh + 12); wrg[4] = F4(wh + 16); }
      L0F1(wr0, 0) L0F1(wr1, 1) L0F1(wr2, 2)
    }
  } else {
    const float* ws = fam ? whh1 : wih1;
#define L1W(wrg, gg) { \
    const float* wp = ws + (size_t)((gg) * kH + jg) * kH + ks * 32;          \
    wrg[0] = F4(wp);      wrg[1] = F4(wp + 4);  wrg[2] = F4(wp + 8);         \
    wrg[3] = F4(wp + 12); wrg[4] = F4(wp + 16); wrg[5] = F4(wp + 20);        \
    wrg[6] = F4(wp + 24); wrg[7] = F4(wp + 28); }
    L1W(wr0, 0) L1W(wr1, 1) L1W(wr2, 2)
  }

  // ---- finisher bias caches ----
  // finish-l0 runs on tid<128 (waves 0-1); finish-l1 on tid in [256,384).
  float fb_r = 0.f, fb_z = 0.f, fn_i = 0.f, fn_h = 0.f;
  if (tid < 128) {
    const int jf = j0 + (tid & 7);
    fb_r = bih0[jf] + bhh0[jf];
    fb_z = bih0[kH + jf] + bhh0[kH + jf];
    fn_i = bih0[2 * kH + jf];
    fn_h = bhh0[2 * kH + jf];
  } else if (tid >= 256 && tid < 384) {
    const int jf = j0 + (tid & 7);
    fb_r = bih1[jf] + bhh1[jf];
    fb_z = bih1[kH + jf] + bhh1[kH + jf];
    fn_i = bih1[2 * kH + jf];
    fn_h = bhh1[2 * kH + jf];
  }

  // sweep indices: 256 threads cover 2048 u64 (8 each). Both sweep roles
  // (h1 on tid>=256 at A, h0 on tid<256 at C) use sidx = tid & 255.
  const int sidx = tid & 255;
  int RO[8], K2[8];
  #pragma unroll
  for (int p = 0; p < 8; ++p) {
    const int i = sidx + p * 256;
    RO[p] = i >> 7; K2[p] = i & 127;
  }

  // ---- prologue: stage h0(-1) (slot 2, tag 0 = memset) + x(0) ----
  if (tid < 256) {
    #pragma unroll
    for (int p = 0; p < 8; ++p) {
      const ull* a0 = (const ull*)(h0w + (size_t)2 * kBH +
                                   (size_t)(r0 + RO[p]) * kH) + K2[p];
      ull v = AL(a0);
      while ((((u32)v | (u32)(v >> 32)) & 3u)) {
        __builtin_amdgcn_s_sleep(1);
        v = AL(a0);
      }
      const int ksg = K2[p] >> 4, off = (K2[p] * 2) & 31;
      float2 f; __builtin_memcpy(&f, &v, 8);
      *(float2*)(lds + O_S0 + ksg * SKS + RO[p] * SRS + off) = f;
    }
  } else {
    const int idx = tid - 256;                 // 0..255
    const int ro = idx >> 4, c4 = (idx & 15) * 4;
    *(float4*)(lds + O_X + ro * 68 + c4) =
        F4(x + (size_t)(r0 + ro) * kT * kI + c4);
  }
  __syncthreads();

  // ---- main loop: 513 rounds x 3 phases ----
  for (int s = 0; s <= kT; ++s) {
    // ================= phase A =================
    if (lay == 0) {
      if (s < kT) {
        // l0 dot (r7 verbatim), reads O_X = x(s), O_S0 = h0(s-1)
        float prr[8], pzz[8], pni[8], pnh[8];
        #pragma unroll
        for (int r = 0; r < 8; ++r) {
          const int ro = rh * 8 + r;
          float pr = 0.f, pz = 0.f, pxi = 0.f, pxh = 0.f;
          if (fam == 0) {
            const float* ax = lds + O_X + ro * 68 + ks * 8;
            const float4 x0 = F4(ax), x1 = F4(ax + 4);
            pr  += dot4(x0, wr0[0]) + dot4(x1, wr0[1]);
            pz  += dot4(x0, wr1[0]) + dot4(x1, wr1[1]);
            pxi += dot4(x0, wr2[0]) + dot4(x1, wr2[1]);
            const float* ah = lds + O_S0 + ks * SKS + ro * SRS;
            #pragma unroll
            for (int i = 0; i < 3; ++i) {
              const float4 hv = F4(ah + i * 4);
              pr  += dot4(hv, wr0[2 + i]);
              pz  += dot4(hv, wr1[2 + i]);
              pxh += dot4(hv, wr2[2 + i]);
            }
          } else {
            const float* ah = lds + O_S0 + ks * SKS + ro * SRS + 12;
            #pragma unroll
            for (int i = 0; i < 5; ++i) {
              const float4 hv = F4(ah + i * 4);
              pr  += dot4(hv, wr0[i]);
              pz  += dot4(hv, wr1[i]);
              pxh += dot4(hv, wr2[i]);
            }
          }
          prr[r] = pr; pzz[r] = pz; pni[r] = pxi; pnh[r] = pxh;
        }
        #pragma unroll
        for (int r = 0; r < 8; ++r) { prr[r] = red8(prr[r]); pzz[r] = red8(pzz[r]); }
        if (fam == 0) {
          #pragma unroll
          for (int r = 0; r < 8; ++r) { pni[r] = red8(pni[r]); pnh[r] = red8(pnh[r]); }
        } else {
          #pragma unroll
          for (int r = 0; r < 8; ++r) pnh[r] = red8(pnh[r]);
        }
        if (ks == 0) {
          #pragma unroll
          for (int r = 0; r < 8; ++r) {
            float* pb = lds + O_PB + ((wave >> 1) * 16 + rh * 8 + r) * SRS + ju;
            pb[0] = prr[r]; pb[8] = pzz[r];
            if (fam == 0) { pb[16] = pni[r]; pb[24] = pnh[r]; }
            else            pb[24] = pnh[r];
          }
        }
      }
    } else {
      if (s >= 1) {
        // sweep h1(s-2): slot (s+1)%3, tag (s-1)&3 -> O_S1
        const int slot1 = (s + 1) % 3;
        const u32 e1 = (u32)((s - 1) & 3);
        const ull* A1[8]; ull v1[8];
        #pragma unroll
        for (int p = 0; p < 8; ++p) {
          A1[p] = (const ull*)(h1w + (size_t)slot1 * kBH +
                               (size_t)(r0 + RO[p]) * kH) + K2[p];
          v1[p] = AL(A1[p]);
        }
        for (;;) {
          u32 bad = 0;
          #pragma unroll
          for (int p = 0; p < 8; ++p)
            bad |= ((u32)v1[p] ^ e1) | ((u32)(v1[p] >> 32) ^ e1);
          if (!(bad & 3u)) break;
          __builtin_amdgcn_s_sleep(1);
          #pragma unroll
          for (int p = 0; p < 8; ++p) v1[p] = AL(A1[p]);
        }
        #pragma unroll
        for (int p = 0; p < 8; ++p) {
          const int ksg = K2[p] >> 4, off = (K2[p] * 2) & 31;
          float2 f; __builtin_memcpy(&f, &v1[p], 8);
          *(float2*)(lds + O_S1 + ksg * SKS + RO[p] * SRS + off) = f;
        }
      }
    }
    __syncthreads();

    // ================= phase B =================
    if (tid < 128) {
      // finish-l0(s): gates + PUBLISH h0(s) (early in the phase)
      if (s < kT) {
        const int rof = tid >> 3, uf = tid & 7, jf = j0 + uf;
        const float* p0 = lds + O_PB + (0 * 16 + rof) * SRS + uf;
        const float* p1 = p0 + 16 * SRS;
        const float rr = sigf(p0[0] + p1[0] + fb_r);
        const float zz = sigf(p0[8] + p1[8] + fb_z);
        const float nn = tanhf(p0[16] + p1[16] + fn_i +
                               rr * (p0[24] + p1[24] + fn_h));
        const float hp = lds[O_S0 + (jf >> 5) * SKS + rof * SRS + (jf & 31)];
        const float hv = (1.f - zz) * nn + zz * hp;
        const u32 bits = (__float_as_uint(hv) & ~3u) | (u32)((s + 1) & 3);
        AS(h0w + (size_t)(s % 3) * kBH + (size_t)(r0 + rof) * kH + jf, bits);
      }
    } else if (tid < 256) {
      // stage x(s+1)
      if (s + 1 < kT) {
        const int t = tid - 128;
        #pragma unroll
        for (int qq = 0; qq < 2; ++qq) {
          const int idx = t + qq * 128;
          const int ro = idx >> 4, c4 = (idx & 15) * 4;
          *(float4*)(lds + O_X + ro * 68 + c4) =
              F4(x + (size_t)(r0 + ro) * kT * kI + (size_t)(s + 1) * kI + c4);
        }
      }
    } else {
      // l1 dot(s-1) (r7 verbatim), reads O_S0 = h0(s-1), O_S1 = h1(s-2)
      if (s >= 1) {
        const float* base = lds + (fam ? O_S1 : O_S0);
        float prr[8], pzz[8], pni[8], pnh[8];
        #pragma unroll
        for (int r = 0; r < 8; ++r) {
          const int ro = rh * 8 + r;
          float pr = 0.f, pz = 0.f, pxi = 0.f, pxh = 0.f;
          const float* aa = base + ks * SKS + ro * SRS;
          #pragma unroll
          for (int i = 0; i < 8; ++i) {
            const float4 av = F4(aa + i * 4);
            pr += dot4(av, wr0[i]);
            pz += dot4(av, wr1[i]);
            if (fam) pxh += dot4(av, wr2[i]);
            else     pxi += dot4(av, wr2[i]);
          }
          prr[r] = pr; pzz[r] = pz; pni[r] = pxi; pnh[r] = pxh;
        }
        #pragma unroll
        for (int r = 0; r < 8; ++r) { prr[r] = red8(prr[r]); pzz[r] = red8(pzz[r]); }
        if (fam == 0) {
          #pragma unroll
          for (int r = 0; r < 8; ++r) pni[r] = red8(pni[r]);
        } else {
          #pragma unroll
          for (int r = 0; r < 8; ++r) pnh[r] = red8(pnh[r]);
        }
        if (ks == 0) {
          #pragma unroll
          for (int r = 0; r < 8; ++r) {
            float* pb = lds + O_PB + ((wave >> 1) * 16 + rh * 8 + r) * SRS + ju;
            pb[0] = prr[r]; pb[8] = pzz[r];
            if (fam == 0) pb[16] = pni[r];
            else          pb[24] = pnh[r];
          }
        }
      }
    }
    __syncthreads();

    // ================= phase C =================
    if (tid >= 256 && tid < 384) {
      // finish-l1(s-1): gates + publish h1(s-1)
      if (s >= 1) {
        const int t = tid - 256;
        const int rof = t >> 3, uf = t & 7, jf = j0 + uf;
        const float* p0 = lds + O_PB + (2 * 16 + rof) * SRS + uf;
        const float* p1 = p0 + 16 * SRS;
        const float rr = sigf(p0[0] + p1[0] + fb_r);
        const float zz = sigf(p0[8] + p1[8] + fb_z);
        const float nn = tanhf(p0[16] + p1[16] + fn_i +
                               rr * (p0[24] + p1[24] + fn_h));
        const float hp = lds[O_S1 + (jf >> 5) * SKS + rof * SRS + (jf & 31)];
        const float hv = (1.f - zz) * nn + zz * hp;
        const u32 bits = (__float_as_uint(hv) & ~3u) | (u32)(s & 3);
        AS(h1w + (size_t)((s - 1) % 3) * kBH + (size_t)(r0 + rof) * kH + jf, bits);
      }
    } else if (tid < 256) {
      // sweep h0(s) (published in B; l1-dot was the propagation window)
      if (s < kT) {
        const int slot0 = s % 3;
        const u32 e0 = (u32)((s + 1) & 3);
        const ull* A0[8]; ull v0[8];
        #pragma unroll
        for (int p = 0; p < 8; ++p) {
          A0[p] = (const ull*)(h0w + (size_t)slot0 * kBH +
                               (size_t)(r0 + RO[p]) * kH) + K2[p];
          v0[p] = AL(A0[p]);
        }
        for (;;) {
          u32 bad = 0;
          #pragma unroll
          for (int p = 0; p < 8; ++p)
            bad |= ((u32)v0[p] ^ e0) | ((u32)(v0[p] >> 32) ^ e0);
          if (!(bad & 3u)) break;
          __builtin_amdgcn_s_sleep(1);
          #pragma unroll
          for (int p = 0; p < 8; ++p) v0[p] = AL(A0[p]);
        }
        #pragma unroll
        for (int p = 0; p < 8; ++p) {
          const int ksg = K2[p] >> 4, off = (K2[p] * 2) & 31;
          float2 f; __builtin_memcpy(&f, &v0[p], 8);
          *(float2*)(lds + O_S0 + ksg * SKS + RO[p] * SRS + off) = f;
        }
      }
    }
    __syncthreads();
  }

  // ---- FC epilogue: group's WG0; h1(T-1) slot (kT-1)%3, tag kT&3 ----
  if (wg == 0 && tid < 256) {
    const int rv = tid >> 4, o = (tid >> 3) & 1, kseg = tid & 7;
    const u32* hf = h1w + (size_t)((kT - 1) % 3) * kBH + (size_t)(r0 + rv) * kH;
    const float* wfc = fcw + (size_t)o * kH;
    float acc = 0.f;
    for (int k = kseg * 32; k < kseg * 32 + 32; ++k) {
      u32 b;
      do {
        b = AL(hf + k);
      } while ((b & 3u) != (u32)(kT & 3));
      acc += fmaxf(__uint_as_float(b), 0.f) * wfc[k];
    }
    acc += __shfl_xor(acc, 1);
    acc += __shfl_xor(acc, 2);
    acc += __shfl_xor(acc, 4);
    if (kseg == 0) out[(r0 + rv) * 2 + o] = acc + fcb[o];
  }
}

extern "C" void kernel_launch(void* const* d_in, const int* in_sizes, int n_in,
                              void* d_out, int out_size, void* d_ws, size_t ws_size,
                              hipStream_t stream) {
  const float* x    = (const float*)d_in[0];
  const float* wih0 = (const float*)d_in[1];
  const float* whh0 = (const float*)d_in[2];
  const float* bih0 = (const float*)d_in[3];
  const float* bhh0 = (const float*)d_in[4];
  const float* wih1 = (const float*)d_in[5];
  const float* whh1 = (const float*)d_in[6];
  const float* bih1 = (const float*)d_in[7];
  const float* bhh1 = (const float*)d_in[8];
  const float* fcw  = (const float*)d_in[9];
  const float* fcb  = (const float*)d_in[10];

  u32* h0w = (u32*)d_ws;                 // [3][B][H] tagged
  u32* h1w = h0w + 3 * kBH;              // [3][B][H] tagged
  float* out = (float*)d_out;

  // zero tagged h buffers (tag 0 == t=-1 state) every call
  hipMemsetAsync(d_ws, 0, (size_t)(6 * kBH) * sizeof(u32), stream);

  gru_persistent<<<NWG, NT, 0, stream>>>(
      x, wih0, whh0, bih0, bhh0, wih1, whh1, bih1, bhh1,
      fcw, fcb, h0w, h1w, out);
}